// Round 4
// baseline (664.856 us; speedup 1.0000x reference)
//
#include <hip/hip_runtime.h>
#include <hip/hip_bf16.h>

#define NN 384
#define CC 128
#define HH 4
#define DD 32
#define QK_SCALE 0.17677669529663687f

typedef float f32x4 __attribute__((ext_vector_type(4)));
typedef short s16x8 __attribute__((ext_vector_type(8)));
typedef short s16x4 __attribute__((ext_vector_type(4)));
typedef unsigned short u16;
typedef unsigned int u32;

__device__ __forceinline__ u16 f2b(float f) {
  union { float f; u32 u; } c; c.f = f;
  u32 u = c.u + 0x7FFFu + ((c.u >> 16) & 1u);
  return (u16)(u >> 16);
}
__device__ __forceinline__ u32 pack2(float a, float b) {
  return (u32)f2b(a) | ((u32)f2b(b) << 16);
}
__device__ __forceinline__ float b2f_lo(u32 u) {
  union { u32 u; float f; } c; c.u = u << 16; return c.f;
}
__device__ __forceinline__ float b2f_hi(u32 u) {
  union { u32 u; float f; } c; c.u = u & 0xFFFF0000u; return c.f;
}
__device__ __forceinline__ s16x4 mk4(u32 a, u32 b) {
  union { u32 u[2]; s16x4 v; } c; c.u[0] = a; c.u[1] = b; return c.v;
}

#define MFMA32(a, b, c) __builtin_amdgcn_mfma_f32_16x16x32_bf16((a), (b), (c), 0, 0, 0)
#define MFMA16(a, b, c) __builtin_amdgcn_mfma_f32_16x16x16bf16_1k((a), (b), (c), 0, 0, 0)

// ---------------------------------------------------------------------------
// K1: LayerNorm + pair-bias (bias stored bf16). One wave per position.
// Extra block (bid==36864) converts the 5 weight matrices to bf16
// (q pre-scaled by 1/sqrt(d)).
// ---------------------------------------------------------------------------
__global__ __launch_bounds__(256) void k_ln_bias(
    const float* __restrict__ pair, const float* __restrict__ ln_w,
    const float* __restrict__ ln_b, const float* __restrict__ bias_w,
    const float* __restrict__ q_w, const float* __restrict__ k_w,
    const float* __restrict__ v_w, const float* __restrict__ g_w,
    const float* __restrict__ o_w, u16* __restrict__ xb,
    u16* __restrict__ biasb, u16* __restrict__ wqk, u16* __restrict__ wv,
    u16* __restrict__ wg, u16* __restrict__ wo) {
  if (blockIdx.x == 36864) {
    // weight conversion: 5 x 128x128 fp32 -> bf16 (as packed u32 pairs)
    const int t = threadIdx.x;
    const float2* q2 = (const float2*)q_w;
    const float2* k2 = (const float2*)k_w;
    const float2* v2 = (const float2*)v_w;
    const float2* g2 = (const float2*)g_w;
    const float2* o2 = (const float2*)o_w;
    u32* dq = (u32*)wqk;
    u32* dk = (u32*)wqk + 8192;
    u32* dv = (u32*)wv;
    u32* dg = (u32*)wg;
    u32* dw = (u32*)wo;
    for (int i = t; i < 8192; i += 256) {
      float2 a = q2[i];
      dq[i] = pack2(a.x * QK_SCALE, a.y * QK_SCALE);
      a = k2[i]; dk[i] = pack2(a.x, a.y);
      a = v2[i]; dv[i] = pack2(a.x, a.y);
      a = g2[i]; dg[i] = pack2(a.x, a.y);
      a = o2[i]; dw[i] = pack2(a.x, a.y);
    }
    return;
  }
  const int wave = threadIdx.x >> 6;
  const int l = threadIdx.x & 63;
  const int p = blockIdx.x * 4 + wave;

  const float2 v = ((const float2*)pair)[(size_t)p * 64 + l];
  float s = v.x + v.y, sq = v.x * v.x + v.y * v.y;
#pragma unroll
  for (int off = 32; off >= 1; off >>= 1) {
    s += __shfl_xor(s, off);
    sq += __shfl_xor(sq, off);
  }
  const float mean = s * (1.0f / 128.0f);
  const float rstd = rsqrtf(sq * (1.0f / 128.0f) - mean * mean + 1e-5f);
  const float2 lw = ((const float2*)ln_w)[l];
  const float2 lb2 = ((const float2*)ln_b)[l];
  const float x0 = (v.x - mean) * rstd * lw.x + lb2.x;
  const float x1 = (v.y - mean) * rstd * lw.y + lb2.y;
  ((u32*)xb)[(size_t)p * 64 + l] = pack2(x0, x1);

#pragma unroll
  for (int h = 0; h < HH; ++h) {
    const float2 bw = ((const float2*)bias_w)[h * 64 + l];
    float bp = x0 * bw.x + x1 * bw.y;
#pragma unroll
    for (int off = 32; off >= 1; off >>= 1) bp += __shfl_xor(bp, off);
    if (l == 0) biasb[(size_t)h * NN * NN + p] = f2b(bp);
  }
}

// ---------------------------------------------------------------------------
// K2: QKV projections, LDS-free. Block = 64 rows of one b; 4 waves.
// Part 1: Q|K via swapped x16 GEMM -> q,k stored [bh][384][32] (8B packed
// stores, d-contig per lane). Part 2: V via normal x32 GEMM -> v^T
// [bh][32][384] (8B packed stores, j-contig per lane).
// ---------------------------------------------------------------------------
__global__ __launch_bounds__(256, 4) void k_qkv(
    const u16* __restrict__ xb, const u16* __restrict__ wqk,
    const u16* __restrict__ wv, u16* __restrict__ qg, u16* __restrict__ kg,
    u16* __restrict__ vtg) {
  const int bid = blockIdx.x;  // 384 * 6
  const int b = bid / 6, jt = bid % 6;
  const int jrow0 = b * NN + jt * 64;
  const int jloc0 = jt * 64;
  const int t = threadIdx.x, w = t >> 6, l = t & 63;
  const int lr = l & 15, lg = l >> 4;

  {  // ---- part 1: Q|K swapped x16; wave w covers n in [w*64, w*64+64)
    const int n0 = w * 64;
    f32x4 acc[4][4];  // [ns][ms]
#pragma unroll
    for (int ns = 0; ns < 4; ++ns)
#pragma unroll
      for (int ms = 0; ms < 4; ++ms) acc[ns][ms] = (f32x4){0.f, 0.f, 0.f, 0.f};
#pragma unroll
    for (int cs = 0; cs < 8; ++cs) {
      s16x4 bx[4];
#pragma unroll
      for (int ms = 0; ms < 4; ++ms)
        bx[ms] = *(const s16x4*)&xb[(size_t)(jrow0 + ms * 16 + lr) * CC +
                                    cs * 16 + lg * 4];
#pragma unroll
      for (int ns = 0; ns < 4; ++ns) {
        const s16x4 aW =
            *(const s16x4*)&wqk[(n0 + ns * 16 + lr) * CC + cs * 16 + lg * 4];
#pragma unroll
        for (int ms = 0; ms < 4; ++ms)
          acc[ns][ms] = MFMA16(aW, bx[ms], acc[ns][ms]);
      }
    }
    u16* base = (n0 >= 128) ? kg : qg;
#pragma unroll
    for (int ns = 0; ns < 4; ++ns) {
      const int n = n0 + ns * 16 + lg * 4;  // + r
      const int h = (n >> 5) & 3, d = n & 31;
#pragma unroll
      for (int ms = 0; ms < 4; ++ms) {
        u32* dst = (u32*)(base + (size_t)(b * 4 + h) * 12288 +
                          (jloc0 + ms * 16 + lr) * 32 + d);
        dst[0] = pack2(acc[ns][ms][0], acc[ns][ms][1]);
        dst[1] = pack2(acc[ns][ms][2], acc[ns][ms][3]);
      }
    }
  }

  {  // ---- part 2: V normal x32 -> v^T
    const int m0 = (w & 1) * 32, n0v = (w >> 1) * 64;
    f32x4 accv[2][4];  // [ms][ns]
#pragma unroll
    for (int ms = 0; ms < 2; ++ms)
#pragma unroll
      for (int ns = 0; ns < 4; ++ns) accv[ms][ns] = (f32x4){0.f, 0.f, 0.f, 0.f};
#pragma unroll
    for (int cs = 0; cs < 4; ++cs) {
      s16x8 ax[2], bw[4];
#pragma unroll
      for (int ms = 0; ms < 2; ++ms)
        ax[ms] = *(const s16x8*)&xb[(size_t)(jrow0 + m0 + ms * 16 + lr) * CC +
                                    cs * 32 + lg * 8];
#pragma unroll
      for (int ns = 0; ns < 4; ++ns)
        bw[ns] =
            *(const s16x8*)&wv[(n0v + ns * 16 + lr) * CC + cs * 32 + lg * 8];
#pragma unroll
      for (int ms = 0; ms < 2; ++ms)
#pragma unroll
        for (int ns = 0; ns < 4; ++ns)
          accv[ms][ns] = MFMA32(ax[ms], bw[ns], accv[ms][ns]);
    }
#pragma unroll
    for (int ms = 0; ms < 2; ++ms) {
#pragma unroll
      for (int ns = 0; ns < 4; ++ns) {
        const int n = n0v + ns * 16 + lr;
        const int h = n >> 5, d = n & 31;
        const int j = jloc0 + m0 + ms * 16 + lg * 4;
        u32* dst = (u32*)(vtg + (size_t)(b * 4 + h) * 12288 + d * NN + j);
        dst[0] = pack2(accv[ms][ns][0], accv[ms][ns][1]);
        dst[1] = pack2(accv[ms][ns][2], accv[ms][ns][3]);
      }
    }
  }
}

// ---------------------------------------------------------------------------
// K3: flash attention, swapped QK^T, LDS-free (only 1.5 KB mask in LDS).
// Block = 4 waves x 48 queries = 192 queries; grid = bh*2.
// S^T = mfma32(K_frag, Q_frag) -> lane: query i = lane&15 (softmax is
// lane-local + 2 shuffles); P's 4-contig j per lane feeds x16 PV directly.
// O accumulated as O^T (d rows, i cols) so softmax scale is lane-local.
// ---------------------------------------------------------------------------
__global__ __launch_bounds__(256, 3) void k_attn(
    const u16* __restrict__ qg, const u16* __restrict__ kg,
    const u16* __restrict__ vtg, const u16* __restrict__ biasb,
    const float* __restrict__ mask, float* __restrict__ io) {
  __shared__ float mb[NN];
  const int bid = blockIdx.x;
  const int bh = bid >> 1, half = bid & 1;
  const int b = bh >> 2, h = bh & 3;
  const int t = threadIdx.x, w = t >> 6, l = t & 63;
  const int lr = l & 15, lg = l >> 4;

  for (int i = t; i < NN; i += 256) mb[i] = 1e9f * (mask[b * NN + i] - 1.0f);
  __syncthreads();

  const int q0 = half * 192 + w * 48;
  const u16* qb = qg + (size_t)bh * 12288;
  const u16* kb = kg + (size_t)bh * 12288;
  const u16* vb = vtg + (size_t)bh * 12288;
  const u16* bb = biasb + (size_t)h * NN * NN;

  s16x8 bQ[3];
#pragma unroll
  for (int ms = 0; ms < 3; ++ms)
    bQ[ms] = *(const s16x8*)&qb[(q0 + ms * 16 + lr) * 32 + lg * 8];

  float mr[3], ls[3];
  f32x4 oa[3][2];
#pragma unroll
  for (int ms = 0; ms < 3; ++ms) {
    mr[ms] = -3.0e38f;
    ls[ms] = 0.f;
    oa[ms][0] = (f32x4){0.f, 0.f, 0.f, 0.f};
    oa[ms][1] = (f32x4){0.f, 0.f, 0.f, 0.f};
  }
  const f32x4 z4 = {0.f, 0.f, 0.f, 0.f};

  for (int kt = 0; kt < 6; ++kt) {
    s16x8 aK[4];
#pragma unroll
    for (int js = 0; js < 4; ++js)
      aK[js] = *(const s16x8*)&kb[(kt * 64 + js * 16 + lr) * 32 + lg * 8];

    f32x4 sT[3][4];  // rows j = kt*64+js*16+lg*4+r, col i = q0+ms*16+lr
#pragma unroll
    for (int ms = 0; ms < 3; ++ms)
#pragma unroll
      for (int js = 0; js < 4; ++js) sT[ms][js] = MFMA32(aK[js], bQ[ms], z4);

#pragma unroll
    for (int js = 0; js < 4; ++js) {
      const int jb = kt * 64 + js * 16 + lg * 4;
      const f32x4 m4 = *(const f32x4*)&mb[jb];
#pragma unroll
      for (int ms = 0; ms < 3; ++ms) {
        const u32* bp = (const u32*)&bb[(size_t)(q0 + ms * 16 + lr) * NN + jb];
        const u32 b0 = bp[0], b1 = bp[1];
        sT[ms][js][0] += b2f_lo(b0) + m4[0];
        sT[ms][js][1] += b2f_hi(b0) + m4[1];
        sT[ms][js][2] += b2f_lo(b1) + m4[2];
        sT[ms][js][3] += b2f_hi(b1) + m4[3];
      }
    }

    u32 pk[3][4][2];
#pragma unroll
    for (int ms = 0; ms < 3; ++ms) {
      float tm = -3.0e38f;
#pragma unroll
      for (int js = 0; js < 4; ++js)
#pragma unroll
        for (int r = 0; r < 4; ++r) tm = fmaxf(tm, sT[ms][js][r]);
      tm = fmaxf(tm, __shfl_xor(tm, 16));
      tm = fmaxf(tm, __shfl_xor(tm, 32));
      const float nm = fmaxf(mr[ms], tm);
      const float sc = __expf(mr[ms] - nm);
      mr[ms] = nm;
      float ts = 0.f;
#pragma unroll
      for (int js = 0; js < 4; ++js)
#pragma unroll
        for (int r = 0; r < 4; ++r) {
          const float p = __expf(sT[ms][js][r] - nm);
          sT[ms][js][r] = p;
          ts += p;
        }
      ts += __shfl_xor(ts, 16);
      ts += __shfl_xor(ts, 32);
      ls[ms] = ls[ms] * sc + ts;
      oa[ms][0] *= sc;
      oa[ms][1] *= sc;
#pragma unroll
      for (int js = 0; js < 4; ++js) {
        pk[ms][js][0] = pack2(sT[ms][js][0], sT[ms][js][1]);
        pk[ms][js][1] = pack2(sT[ms][js][2], sT[ms][js][3]);
      }
    }

    // PV: O^T += V^T * P^T via x16 mfma; A = V^T frag (8B global), B = pk.
#pragma unroll
    for (int st = 0; st < 4; ++st) {
      const int jb = kt * 64 + st * 16 + lg * 4;
      s16x4 aV[2];
#pragma unroll
      for (int ns = 0; ns < 2; ++ns)
        aV[ns] = *(const s16x4*)&vb[(ns * 16 + lr) * NN + jb];
#pragma unroll
      for (int ms = 0; ms < 3; ++ms) {
        const s16x4 pb = mk4(pk[ms][st][0], pk[ms][st][1]);
#pragma unroll
        for (int ns = 0; ns < 2; ++ns)
          oa[ms][ns] = MFMA16(aV[ns], pb, oa[ms][ns]);
      }
    }
  }

  // epilogue: O^T lane holds d = ns*16+lg*4+r (rows), i = q0+ms*16+lr (col)
#pragma unroll
  for (int ms = 0; ms < 3; ++ms) {
    const float inv = 1.0f / ls[ms];
    float* orow = io + ((size_t)b * NN + q0 + ms * 16 + lr) * CC + h * DD;
#pragma unroll
    for (int ns = 0; ns < 2; ++ns) {
      f32x4 vo = oa[ms][ns];
      vo *= inv;
      *(f32x4*)&orow[ns * 16 + lg * 4] = vo;
    }
  }
}

// ---------------------------------------------------------------------------
// K4: out = (sigmoid(x@g_w^T) * o) @ o_w^T, LDS-free, all swapped-x16.
// Wave owns 16 rows; gate^T then out^T, both with lane-local row m = lane&15.
// ---------------------------------------------------------------------------
__global__ __launch_bounds__(256, 4) void k_gate_out(
    const u16* __restrict__ xb, const u16* __restrict__ wg,
    const u16* __restrict__ wo, float* __restrict__ io) {
  const int bid = blockIdx.x;  // 2304
  const int t = threadIdx.x, w = t >> 6, l = t & 63;
  const int lr = l & 15, lg = l >> 4;
  const int m0g = bid * 64 + w * 16;  // global row base; row = m0g + lr

  f32x4 a1[8];
#pragma unroll
  for (int ns = 0; ns < 8; ++ns) a1[ns] = (f32x4){0.f, 0.f, 0.f, 0.f};
#pragma unroll
  for (int cs = 0; cs < 8; ++cs) {
    const s16x4 bx =
        *(const s16x4*)&xb[(size_t)(m0g + lr) * CC + cs * 16 + lg * 4];
#pragma unroll
    for (int ns = 0; ns < 8; ++ns) {
      const s16x4 aW =
          *(const s16x4*)&wg[(ns * 16 + lr) * CC + cs * 16 + lg * 4];
      a1[ns] = MFMA16(aW, bx, a1[ns]);
    }
  }

  // gate = sigmoid(a1); as^T = gate * o  (lane: row m0g+lr, cols 4-contig)
  s16x4 pk2[8];
#pragma unroll
  for (int ns = 0; ns < 8; ++ns) {
    const int gc = ns * 16 + lg * 4;
    const f32x4 ov = *(const f32x4*)&io[(size_t)(m0g + lr) * CC + gc];
    float av[4];
#pragma unroll
    for (int r = 0; r < 4; ++r)
      av[r] = ov[r] / (1.0f + __expf(-a1[ns][r]));
    pk2[ns] = mk4(pack2(av[0], av[1]), pack2(av[2], av[3]));
  }

  f32x4 a2[8];
#pragma unroll
  for (int ns = 0; ns < 8; ++ns) a2[ns] = (f32x4){0.f, 0.f, 0.f, 0.f};
#pragma unroll
  for (int cs = 0; cs < 8; ++cs) {
#pragma unroll
    for (int ns = 0; ns < 8; ++ns) {
      const s16x4 aW =
          *(const s16x4*)&wo[(ns * 16 + lr) * CC + cs * 16 + lg * 4];
      a2[ns] = MFMA16(aW, pk2[cs], a2[ns]);
    }
  }
#pragma unroll
  for (int ns = 0; ns < 8; ++ns)
    *(f32x4*)&io[(size_t)(m0g + lr) * CC + ns * 16 + lg * 4] = a2[ns];
}

// ---------------------------------------------------------------------------
extern "C" void kernel_launch(void* const* d_in, const int* in_sizes, int n_in,
                              void* d_out, int out_size, void* d_ws,
                              size_t ws_size, hipStream_t stream) {
  const float* pair = (const float*)d_in[0];
  const float* mask = (const float*)d_in[1];
  const float* ln_w = (const float*)d_in[2];
  const float* ln_b = (const float*)d_in[3];
  const float* bias_w = (const float*)d_in[4];
  const float* q_w = (const float*)d_in[5];
  const float* k_w = (const float*)d_in[6];
  const float* v_w = (const float*)d_in[7];
  const float* g_w = (const float*)d_in[8];
  const float* o_w = (const float*)d_in[9];

  char* wsb = (char*)d_ws;
  u16* xb = (u16*)wsb;                       // 37,748,736 B
  u16* biasb = (u16*)(wsb + 37748736);       //  1,179,648 B (bf16)
  u16* wqk = (u16*)(wsb + 38928384);         //     65,536 B (q scaled | k)
  u16* wv = (u16*)(wsb + 38993920);          //     32,768 B
  u16* wg = (u16*)(wsb + 39026688);          //     32,768 B
  u16* wo = (u16*)(wsb + 39059456);          //     32,768 B
  u16* qg = (u16*)(wsb + 39092224);          // 37,748,736 B
  u16* kg = (u16*)(wsb + 76840960);          // 37,748,736 B
  u16* vtg = (u16*)(wsb + 114589696);        // 37,748,736 B -> 152,338,432
  float* io = (float*)d_out;

  hipLaunchKernelGGL(k_ln_bias, dim3(NN * NN / 4 + 1), dim3(256), 0, stream,
                     pair, ln_w, ln_b, bias_w, q_w, k_w, v_w, g_w, o_w, xb,
                     biasb, wqk, wv, wg, wo);
  hipLaunchKernelGGL(k_qkv, dim3(NN * 6), dim3(256), 0, stream, xb, wqk, wv,
                     qg, kg, vtg);
  hipLaunchKernelGGL(k_attn, dim3(NN * HH * 2), dim3(256), 0, stream, qg, kg,
                     vtg, biasb, mask, io);
  hipLaunchKernelGGL(k_gate_out, dim3(NN * NN / 64), dim3(256), 0, stream, xb,
                     g_w ? wg : wg, wo, io);
}

// Round 5
// 620.547 us; speedup vs baseline: 1.0714x; 1.0714x over previous
//
#include <hip/hip_runtime.h>
#include <hip/hip_bf16.h>

#define NN 384
#define CC 128
#define HH 4
#define QK_SCALE 0.17677669529663687f

typedef float f32x4 __attribute__((ext_vector_type(4)));
typedef short s16x8 __attribute__((ext_vector_type(8)));
typedef short s16x4 __attribute__((ext_vector_type(4)));
typedef unsigned short u16;
typedef unsigned int u32;

__device__ __forceinline__ u16 f2b(float f) {
  union { float f; u32 u; } c; c.f = f;
  u32 u = c.u + 0x7FFFu + ((c.u >> 16) & 1u);
  return (u16)(u >> 16);
}
__device__ __forceinline__ u32 pack2(float a, float b) {
  return (u32)f2b(a) | ((u32)f2b(b) << 16);
}
// truncating pack (P in [0,1], normalized by fp32 sum afterwards)
__device__ __forceinline__ u32 pack2t(float a, float b) {
  union { float f; u32 u; } x, y; x.f = a; y.f = b;
  return (x.u >> 16) | (y.u & 0xFFFF0000u);
}
__device__ __forceinline__ float b2f_lo(u32 u) {
  union { u32 u; float f; } c; c.u = u << 16; return c.f;
}
__device__ __forceinline__ float b2f_hi(u32 u) {
  union { u32 u; float f; } c; c.u = u & 0xFFFF0000u; return c.f;
}
__device__ __forceinline__ s16x4 mk4(u32 a, u32 b) {
  union { u32 u[2]; s16x4 v; } c; c.u[0] = a; c.u[1] = b; return c.v;
}

#define MFMA32(a, b, c) __builtin_amdgcn_mfma_f32_16x16x32_bf16((a), (b), (c), 0, 0, 0)
#define MFMA16(a, b, c) __builtin_amdgcn_mfma_f32_16x16x16bf16_1k((a), (b), (c), 0, 0, 0)

// ---------------------------------------------------------------------------
// K1: LayerNorm + pair-bias. One wave per position p=(i,j). x -> bf16 packed.
// bias written bf16 in FRAGMENT-TILED layout:
//   elem (h,i,j) at tile (h, jt=j>>4, it=i>>4), slot = ((j&12)<<2 | (i&15))*4 + (j&3)
// Extra block converts the 5 weight matrices to bf16 (q pre-scaled).
// ---------------------------------------------------------------------------
__global__ __launch_bounds__(256) void k_ln_bias(
    const float* __restrict__ pair, const float* __restrict__ ln_w,
    const float* __restrict__ ln_b, const float* __restrict__ bias_w,
    const float* __restrict__ q_w, const float* __restrict__ k_w,
    const float* __restrict__ v_w, const float* __restrict__ g_w,
    const float* __restrict__ o_w, u16* __restrict__ xb,
    u16* __restrict__ biasf, u16* __restrict__ wqk, u16* __restrict__ wv,
    u16* __restrict__ wg, u16* __restrict__ wo) {
  if (blockIdx.x == 36864) {
    const int t = threadIdx.x;
    const float2* q2 = (const float2*)q_w;
    const float2* k2 = (const float2*)k_w;
    const float2* v2 = (const float2*)v_w;
    const float2* g2 = (const float2*)g_w;
    const float2* o2 = (const float2*)o_w;
    u32* dq = (u32*)wqk;
    u32* dk = (u32*)wqk + 8192;
    u32* dv = (u32*)wv;
    u32* dg = (u32*)wg;
    u32* dw = (u32*)wo;
    for (int i = t; i < 8192; i += 256) {
      float2 a = q2[i];
      dq[i] = pack2(a.x * QK_SCALE, a.y * QK_SCALE);
      a = k2[i]; dk[i] = pack2(a.x, a.y);
      a = v2[i]; dv[i] = pack2(a.x, a.y);
      a = g2[i]; dg[i] = pack2(a.x, a.y);
      a = o2[i]; dw[i] = pack2(a.x, a.y);
    }
    return;
  }
  const int wave = threadIdx.x >> 6;
  const int l = threadIdx.x & 63;
  const int p = blockIdx.x * 4 + wave;

  const float2 v = ((const float2*)pair)[(size_t)p * 64 + l];
  float s = v.x + v.y, sq = v.x * v.x + v.y * v.y;
#pragma unroll
  for (int off = 32; off >= 1; off >>= 1) {
    s += __shfl_xor(s, off);
    sq += __shfl_xor(sq, off);
  }
  const float mean = s * (1.0f / 128.0f);
  const float rstd = rsqrtf(sq * (1.0f / 128.0f) - mean * mean + 1e-5f);
  const float2 lw = ((const float2*)ln_w)[l];
  const float2 lb2 = ((const float2*)ln_b)[l];
  const float x0 = (v.x - mean) * rstd * lw.x + lb2.x;
  const float x1 = (v.y - mean) * rstd * lw.y + lb2.y;
  ((u32*)xb)[(size_t)p * 64 + l] = pack2(x0, x1);

  const int i = p / NN;
  const int j = p - i * NN;
  const int slot = ((j & 12) << 4) + ((i & 15) << 2) + (j & 3);
#pragma unroll
  for (int h = 0; h < HH; ++h) {
    const float2 bw = ((const float2*)bias_w)[h * 64 + l];
    float bp = x0 * bw.x + x1 * bw.y;
#pragma unroll
    for (int off = 32; off >= 1; off >>= 1) bp += __shfl_xor(bp, off);
    if (l == 0)
      biasf[(((h * 24 + (j >> 4)) * 24 + (i >> 4)) << 8) + slot] = f2b(bp);
  }
}

// ---------------------------------------------------------------------------
// K2: QKV projections. Block = 64 rows of one b; 4 waves; all x32 MFMA.
// Part1 (swapped, A=W): wave w covers cols n0=w*64 of [q|k] -> q,k [bh][384][32]
// Part2 (normal, A=x): V -> vtf in FRAGMENT-TILED layout [bh][jt][dt][256].
// x fragments are shared between the two parts.
// ---------------------------------------------------------------------------
__global__ __launch_bounds__(256) void k_qkv(
    const u16* __restrict__ xb, const u16* __restrict__ wqk,
    const u16* __restrict__ wv, u16* __restrict__ qg, u16* __restrict__ kg,
    u16* __restrict__ vtf) {
  const int bid = blockIdx.x;  // 384*6
  const int b = bid / 6, jt6 = bid % 6;
  const int jrow0 = b * NN + jt6 * 64, jloc0 = jt6 * 64;
  const int t = threadIdx.x, w = t >> 6, l = t & 63;
  const int lr = l & 15, lg = l >> 4;
  const int n0 = w * 64;          // part1 col base in [q|k] (0..255)
  const int m0v = (w & 1) * 2;    // part2: x-frag tile index base
  const int n0v = (w >> 1) * 64;  // part2 col base (0..127)

  f32x4 acc[4][4];   // [ns][ms] part1
  f32x4 accv[2][4];  // [mv][ns] part2
#pragma unroll
  for (int a = 0; a < 4; ++a)
#pragma unroll
    for (int c = 0; c < 4; ++c) acc[a][c] = (f32x4){0.f, 0.f, 0.f, 0.f};
#pragma unroll
  for (int a = 0; a < 2; ++a)
#pragma unroll
    for (int c = 0; c < 4; ++c) accv[a][c] = (f32x4){0.f, 0.f, 0.f, 0.f};

#pragma unroll
  for (int cs = 0; cs < 4; ++cs) {
    s16x8 bx[4];
#pragma unroll
    for (int ms = 0; ms < 4; ++ms)
      bx[ms] = *(const s16x8*)&xb[(size_t)(jrow0 + ms * 16 + lr) * CC +
                                  cs * 32 + lg * 8];
#pragma unroll
    for (int ns = 0; ns < 4; ++ns) {
      const s16x8 aW =
          *(const s16x8*)&wqk[(n0 + ns * 16 + lr) * CC + cs * 32 + lg * 8];
#pragma unroll
      for (int ms = 0; ms < 4; ++ms)
        acc[ns][ms] = MFMA32(aW, bx[ms], acc[ns][ms]);
      const s16x8 bV =
          *(const s16x8*)&wv[(n0v + ns * 16 + lr) * CC + cs * 32 + lg * 8];
#pragma unroll
      for (int mv = 0; mv < 2; ++mv)
        accv[mv][ns] = MFMA32(bx[m0v + mv], bV, accv[mv][ns]);
    }
  }

  // part1 write: q,k row-major [bh][j][32]; lane: j = jloc0+ms*16+lr, d0 4-contig
  {
    u16* base = (n0 >= 128) ? kg : qg;
    const int nb = n0 & 64;
#pragma unroll
    for (int ns = 0; ns < 4; ++ns) {
      const int nl = nb + ns * 16 + lg * 4;  // 0..127
      const int h = nl >> 5, d0 = nl & 31;
#pragma unroll
      for (int ms = 0; ms < 4; ++ms) {
        u32* dst = (u32*)(base + (size_t)(b * 4 + h) * 12288 +
                          (jloc0 + ms * 16 + lr) * 32 + d0);
        dst[0] = pack2(acc[ns][ms][0], acc[ns][ms][1]);
        dst[1] = pack2(acc[ns][ms][2], acc[ns][ms][3]);
      }
    }
  }

  // part2 write: vtf fragment-tiled; lane l owns u32 slots [2l, 2l+2) of tile
#pragma unroll
  for (int mv = 0; mv < 2; ++mv) {
#pragma unroll
    for (int ns = 0; ns < 4; ++ns) {
      const int n = n0v + ns * 16 + lr;  // h*32 + d
      const int h = n >> 5;
      const int dt = (n >> 4) & 1;
      const int j0 = jloc0 + (m0v + mv) * 16;
      u32* dst = (u32*)vtf +
                 ((((size_t)(b * 4 + h)) * 24 + (j0 >> 4)) * 2 + dt) * 128 +
                 l * 2;
      dst[0] = pack2(accv[mv][ns][0], accv[mv][ns][1]);
      dst[1] = pack2(accv[mv][ns][2], accv[mv][ns][3]);
    }
  }
}

// ---------------------------------------------------------------------------
// K3: flash attention, swapped QK^T. LDS only for mask (1.5 KB).
// All per-kt loads coalesced (K 16B row-frags; bias & V^T fragment-tiled 8B)
// and hoisted to the top of each fully-unrolled iteration.
// ---------------------------------------------------------------------------
__global__ __launch_bounds__(256) void k_attn(
    const u16* __restrict__ qg, const u16* __restrict__ kg,
    const u16* __restrict__ vtf, const u16* __restrict__ biasf,
    const float* __restrict__ mask, float* __restrict__ io) {
  __shared__ float mb[NN];
  const int bid = blockIdx.x;
  const int bh = bid >> 1, half = bid & 1;
  const int b = bh >> 2, h = bh & 3;
  const int t = threadIdx.x, w = t >> 6, l = t & 63;
  const int lr = l & 15, lg = l >> 4;

  for (int i = t; i < NN; i += 256) mb[i] = 1e9f * (mask[b * NN + i] - 1.0f);
  __syncthreads();

  const int q0 = half * 192 + w * 48, it0 = q0 >> 4;
  const u16* qb = qg + (size_t)bh * 12288;
  const u16* kb = kg + (size_t)bh * 12288;
  const u32* vt = (const u32*)vtf + (size_t)bh * 6144;
  const u32* bbf = (const u32*)biasf + (size_t)h * 73728;

  s16x8 bQ[3];
#pragma unroll
  for (int ms = 0; ms < 3; ++ms)
    bQ[ms] = *(const s16x8*)&qb[(q0 + ms * 16 + lr) * 32 + lg * 8];

  float mr[3], ls[3];
  f32x4 oa[3][2];
#pragma unroll
  for (int ms = 0; ms < 3; ++ms) {
    mr[ms] = -3.0e38f;
    ls[ms] = 0.f;
    oa[ms][0] = (f32x4){0.f, 0.f, 0.f, 0.f};
    oa[ms][1] = (f32x4){0.f, 0.f, 0.f, 0.f};
  }
  const f32x4 z4 = {0.f, 0.f, 0.f, 0.f};

#pragma unroll
  for (int kt = 0; kt < 6; ++kt) {
    // ---- all loads issued up-front (coalesced) ----
    s16x8 aK[4];
#pragma unroll
    for (int js = 0; js < 4; ++js)
      aK[js] = *(const s16x8*)&kb[(kt * 64 + js * 16 + lr) * 32 + lg * 8];
    u32 bw[3][4][2];
#pragma unroll
    for (int ms = 0; ms < 3; ++ms)
#pragma unroll
      for (int js = 0; js < 4; ++js) {
        const u32* p = bbf + ((kt * 4 + js) * 24 + it0 + ms) * 128 + l * 2;
        bw[ms][js][0] = p[0];
        bw[ms][js][1] = p[1];
      }
    s16x4 aV[4][2];
#pragma unroll
    for (int st = 0; st < 4; ++st)
#pragma unroll
      for (int ns = 0; ns < 2; ++ns)
        aV[st][ns] =
            *(const s16x4*)(vt + ((kt * 4 + st) * 2 + ns) * 128 + l * 2);

    // ---- QK^T (S^T: lane j = lg*4+r within js-tile, query i = lr) ----
    f32x4 sT[3][4];
#pragma unroll
    for (int ms = 0; ms < 3; ++ms)
#pragma unroll
      for (int js = 0; js < 4; ++js) sT[ms][js] = MFMA32(aK[js], bQ[ms], z4);

    // ---- bias + mask ----
#pragma unroll
    for (int js = 0; js < 4; ++js) {
      const int jb = kt * 64 + js * 16 + lg * 4;
      const f32x4 m4 = *(const f32x4*)&mb[jb];
#pragma unroll
      for (int ms = 0; ms < 3; ++ms) {
        const u32 b0 = bw[ms][js][0], b1 = bw[ms][js][1];
        sT[ms][js][0] += b2f_lo(b0) + m4[0];
        sT[ms][js][1] += b2f_hi(b0) + m4[1];
        sT[ms][js][2] += b2f_lo(b1) + m4[2];
        sT[ms][js][3] += b2f_hi(b1) + m4[3];
      }
    }

    // ---- online softmax (row i lives in {lr, lr+16, lr+32, lr+48}) ----
    u32 pk[3][4][2];
#pragma unroll
    for (int ms = 0; ms < 3; ++ms) {
      float tm = -3.0e38f;
#pragma unroll
      for (int js = 0; js < 4; ++js)
#pragma unroll
        for (int r = 0; r < 4; ++r) tm = fmaxf(tm, sT[ms][js][r]);
      tm = fmaxf(tm, __shfl_xor(tm, 16));
      tm = fmaxf(tm, __shfl_xor(tm, 32));
      const float nm = fmaxf(mr[ms], tm);
      const float sc = __expf(mr[ms] - nm);
      mr[ms] = nm;
      float ts = 0.f;
#pragma unroll
      for (int js = 0; js < 4; ++js)
#pragma unroll
        for (int r = 0; r < 4; ++r) {
          const float p = __expf(sT[ms][js][r] - nm);
          sT[ms][js][r] = p;
          ts += p;
        }
      ts += __shfl_xor(ts, 16);
      ts += __shfl_xor(ts, 32);
      ls[ms] = ls[ms] * sc + ts;
      oa[ms][0] *= sc;
      oa[ms][1] *= sc;
#pragma unroll
      for (int js = 0; js < 4; ++js) {
        pk[ms][js][0] = pack2t(sT[ms][js][0], sT[ms][js][1]);
        pk[ms][js][1] = pack2t(sT[ms][js][2], sT[ms][js][3]);
      }
    }

    // ---- PV: O^T += V^T * P^T (x16 mfma, everything in registers) ----
#pragma unroll
    for (int st = 0; st < 4; ++st) {
#pragma unroll
      for (int ms = 0; ms < 3; ++ms) {
        const s16x4 pb = mk4(pk[ms][st][0], pk[ms][st][1]);
#pragma unroll
        for (int ns = 0; ns < 2; ++ns)
          oa[ms][ns] = MFMA16(aV[st][ns], pb, oa[ms][ns]);
      }
    }
  }

  // epilogue: lane holds O^T: d = ns*16+lg*4+r, query i = q0+ms*16+lr
#pragma unroll
  for (int ms = 0; ms < 3; ++ms) {
    const float inv = 1.0f / ls[ms];
    float* orow = io + ((size_t)b * NN + q0 + ms * 16 + lr) * CC + h * 32;
#pragma unroll
    for (int ns = 0; ns < 2; ++ns) {
      f32x4 vo = oa[ms][ns];
      vo *= inv;
      *(f32x4*)&orow[ns * 16 + lg * 4] = vo;
    }
  }
}

// ---------------------------------------------------------------------------
// K4: out = (sigmoid(x@g_w^T) * o) @ o_w^T. LDS-free.
// GEMM1: x32 swapped (A=wg) -> lane holds gate(i=lr, c = ns*16+lg*4+r),
// which is exactly the x16 B-frag layout GEMM2 needs (zero shuffles).
// ---------------------------------------------------------------------------
__global__ __launch_bounds__(256) void k_gate_out(
    const u16* __restrict__ xb, const u16* __restrict__ wg,
    const u16* __restrict__ wo, float* __restrict__ io) {
  const int bid = blockIdx.x;  // 2304
  const int t = threadIdx.x, w = t >> 6, l = t & 63;
  const int lr = l & 15, lg = l >> 4;
  const int m0g = bid * 64 + w * 16;  // wave's 16 rows: m0g + lr

  f32x4 a1[8];
#pragma unroll
  for (int ns = 0; ns < 8; ++ns) a1[ns] = (f32x4){0.f, 0.f, 0.f, 0.f};
#pragma unroll
  for (int cs = 0; cs < 4; ++cs) {
    const s16x8 bx =
        *(const s16x8*)&xb[(size_t)(m0g + lr) * CC + cs * 32 + lg * 8];
#pragma unroll
    for (int ns = 0; ns < 8; ++ns) {
      const s16x8 aW =
          *(const s16x8*)&wg[(ns * 16 + lr) * CC + cs * 32 + lg * 8];
      a1[ns] = MFMA32(aW, bx, a1[ns]);
    }
  }

  s16x4 pk2[8];
#pragma unroll
  for (int ns = 0; ns < 8; ++ns) {
    const f32x4 ov =
        *(const f32x4*)&io[(size_t)(m0g + lr) * CC + ns * 16 + lg * 4];
    float av[4];
#pragma unroll
    for (int r = 0; r < 4; ++r)
      av[r] = ov[r] / (1.0f + __expf(-a1[ns][r]));
    pk2[ns] = mk4(pack2(av[0], av[1]), pack2(av[2], av[3]));
  }

  f32x4 a2[8];
#pragma unroll
  for (int ns = 0; ns < 8; ++ns) a2[ns] = (f32x4){0.f, 0.f, 0.f, 0.f};
#pragma unroll
  for (int cs = 0; cs < 8; ++cs) {
#pragma unroll
    for (int ns = 0; ns < 8; ++ns) {
      const s16x4 aW2 =
          *(const s16x4*)&wo[(ns * 16 + lr) * CC + cs * 16 + lg * 4];
      a2[ns] = MFMA16(aW2, pk2[cs], a2[ns]);
    }
  }
#pragma unroll
  for (int ns = 0; ns < 8; ++ns)
    *(f32x4*)&io[(size_t)(m0g + lr) * CC + ns * 16 + lg * 4] = a2[ns];
}

// ---------------------------------------------------------------------------
extern "C" void kernel_launch(void* const* d_in, const int* in_sizes, int n_in,
                              void* d_out, int out_size, void* d_ws,
                              size_t ws_size, hipStream_t stream) {
  const float* pair = (const float*)d_in[0];
  const float* mask = (const float*)d_in[1];
  const float* ln_w = (const float*)d_in[2];
  const float* ln_b = (const float*)d_in[3];
  const float* bias_w = (const float*)d_in[4];
  const float* q_w = (const float*)d_in[5];
  const float* k_w = (const float*)d_in[6];
  const float* v_w = (const float*)d_in[7];
  const float* g_w = (const float*)d_in[8];
  const float* o_w = (const float*)d_in[9];

  char* wsb = (char*)d_ws;
  u16* xb = (u16*)wsb;                       // 37,748,736 B
  u16* biasf = (u16*)(wsb + 37748736);       //  1,179,648 B (bf16 frag-tiled)
  u16* wqk = (u16*)(wsb + 38928384);         //     65,536 B
  u16* wv = (u16*)(wsb + 38993920);          //     32,768 B
  u16* wg = (u16*)(wsb + 39026688);          //     32,768 B
  u16* wo = (u16*)(wsb + 39059456);          //     32,768 B
  u16* qg = (u16*)(wsb + 39092224);          // 37,748,736 B
  u16* kg = (u16*)(wsb + 76840960);          // 37,748,736 B
  u16* vtf = (u16*)(wsb + 114589696);        // 37,748,736 B (frag-tiled)
  float* io = (float*)d_out;

  hipLaunchKernelGGL(k_ln_bias, dim3(NN * NN / 4 + 1), dim3(256), 0, stream,
                     pair, ln_w, ln_b, bias_w, q_w, k_w, v_w, g_w, o_w, xb,
                     biasf, wqk, wv, wg, wo);
  hipLaunchKernelGGL(k_qkv, dim3(NN * 6), dim3(256), 0, stream, xb, wqk, wv,
                     qg, kg, vtf);
  hipLaunchKernelGGL(k_attn, dim3(NN * HH * 2), dim3(256), 0, stream, qg, kg,
                     vtf, biasf, mask, io);
  hipLaunchKernelGGL(k_gate_out, dim3(NN * NN / 64), dim3(256), 0, stream, xb,
                     wg, wo, io);
}

// Round 7
// 570.900 us; speedup vs baseline: 1.1646x; 1.0870x over previous
//
#include <hip/hip_runtime.h>
#include <hip/hip_bf16.h>

#define NN 384
#define CC 128
#define HH 4
#define QK_SCALE 0.17677669529663687f
#define LOG2E 1.4426950408889634f
#define SMAX 20.0f

typedef float f32x4 __attribute__((ext_vector_type(4)));
typedef short s16x8 __attribute__((ext_vector_type(8)));
typedef short s16x4 __attribute__((ext_vector_type(4)));
typedef unsigned short u16;
typedef unsigned int u32;

__device__ __forceinline__ u16 f2b(float f) {
  union { float f; u32 u; } c; c.f = f;
  u32 u = c.u + 0x7FFFu + ((c.u >> 16) & 1u);
  return (u16)(u >> 16);
}
__device__ __forceinline__ u32 pack2(float a, float b) {
  return (u32)f2b(a) | ((u32)f2b(b) << 16);
}
// truncating pack (p >= 0, normalized by fp32 sum afterwards)
__device__ __forceinline__ u32 pack2t(float a, float b) {
  union { float f; u32 u; } x, y; x.f = a; y.f = b;
  return (x.u >> 16) | (y.u & 0xFFFF0000u);
}
__device__ __forceinline__ float b2f_lo(u32 u) {
  union { u32 u; float f; } c; c.u = u << 16; return c.f;
}
__device__ __forceinline__ float b2f_hi(u32 u) {
  union { u32 u; float f; } c; c.u = u & 0xFFFF0000u; return c.f;
}
__device__ __forceinline__ s16x4 mk4(u32 a, u32 b) {
  union { u32 u[2]; s16x4 v; } c; c.u[0] = a; c.u[1] = b; return c.v;
}

#define MFMA32(a, b, c) __builtin_amdgcn_mfma_f32_16x16x32_bf16((a), (b), (c), 0, 0, 0)
#define MFMA16(a, b, c) __builtin_amdgcn_mfma_f32_16x16x16bf16_1k((a), (b), (c), 0, 0, 0)

// ---------------------------------------------------------------------------
// K1: LayerNorm + pair-bias. One wave per position p=(i,j). x -> bf16 packed.
// bias written bf16 (pre-scaled by LOG2E) in fragment-tiled layout:
//   tile (h, jt=j>>4, it=i>>4), slot = ((j&12)<<4) + ((i&15)<<2) + (j&3)
// Extra block converts the 5 weight matrices to bf16 (wq scaled by
// QK_SCALE*LOG2E).
// ---------------------------------------------------------------------------
__global__ __launch_bounds__(256) void k_ln_bias(
    const float* __restrict__ pair, const float* __restrict__ ln_w,
    const float* __restrict__ ln_b, const float* __restrict__ bias_w,
    const float* __restrict__ q_w, const float* __restrict__ k_w,
    const float* __restrict__ v_w, const float* __restrict__ g_w,
    const float* __restrict__ o_w, u16* __restrict__ xb,
    u16* __restrict__ biasf, u16* __restrict__ wqk, u16* __restrict__ wv,
    u16* __restrict__ wg, u16* __restrict__ wo) {
  if (blockIdx.x == 36864) {
    const int t = threadIdx.x;
    const float2* q2 = (const float2*)q_w;
    const float2* k2 = (const float2*)k_w;
    const float2* v2 = (const float2*)v_w;
    const float2* g2 = (const float2*)g_w;
    const float2* o2 = (const float2*)o_w;
    u32* dq = (u32*)wqk;
    u32* dk = (u32*)wqk + 8192;
    u32* dv = (u32*)wv;
    u32* dg = (u32*)wg;
    u32* dw = (u32*)wo;
    const float qs = QK_SCALE * LOG2E;
    for (int i = t; i < 8192; i += 256) {
      float2 a = q2[i];
      dq[i] = pack2(a.x * qs, a.y * qs);
      a = k2[i]; dk[i] = pack2(a.x, a.y);
      a = v2[i]; dv[i] = pack2(a.x, a.y);
      a = g2[i]; dg[i] = pack2(a.x, a.y);
      a = o2[i]; dw[i] = pack2(a.x, a.y);
    }
    return;
  }
  const int wave = threadIdx.x >> 6;
  const int l = threadIdx.x & 63;
  const int p = blockIdx.x * 4 + wave;

  const float2 v = ((const float2*)pair)[(size_t)p * 64 + l];
  float s = v.x + v.y, sq = v.x * v.x + v.y * v.y;
#pragma unroll
  for (int off = 32; off >= 1; off >>= 1) {
    s += __shfl_xor(s, off);
    sq += __shfl_xor(sq, off);
  }
  const float mean = s * (1.0f / 128.0f);
  const float rstd = rsqrtf(sq * (1.0f / 128.0f) - mean * mean + 1e-5f);
  const float2 lw = ((const float2*)ln_w)[l];
  const float2 lb2 = ((const float2*)ln_b)[l];
  const float x0 = (v.x - mean) * rstd * lw.x + lb2.x;
  const float x1 = (v.y - mean) * rstd * lw.y + lb2.y;
  ((u32*)xb)[(size_t)p * 64 + l] = pack2(x0, x1);

  const int i = p / NN;
  const int j = p - i * NN;
  const int slot = ((j & 12) << 4) + ((i & 15) << 2) + (j & 3);
#pragma unroll
  for (int h = 0; h < HH; ++h) {
    const float2 bw = ((const float2*)bias_w)[h * 64 + l];
    float bp = x0 * bw.x + x1 * bw.y;
#pragma unroll
    for (int off = 32; off >= 1; off >>= 1) bp += __shfl_xor(bp, off);
    if (l == 0)
      biasf[(((h * 24 + (j >> 4)) * 24 + (i >> 4)) << 8) + slot] =
          f2b(bp * LOG2E);
  }
}

// ---------------------------------------------------------------------------
// K2-MEGA: per (b, half): QKV proj (into LDS, per head, j-chunked) ->
// attention (swapped QK^T, static-max exp2 softmax) -> gate (in-register) ->
// out-projection (accumulated from stashed (g*o) bf16 frags). One kernel,
// no q/k/v/o global intermediates.
// 256 threads = 4 waves; wave owns 48 query rows.
// ---------------------------------------------------------------------------
__global__ __launch_bounds__(256, 2) void k_mega(
    const u16* __restrict__ xb, const u16* __restrict__ wqk,
    const u16* __restrict__ wv, const u16* __restrict__ wg,
    const u16* __restrict__ wo, const u16* __restrict__ biasf,
    const float* __restrict__ mask, float* __restrict__ io) {
  __shared__ u16 q_lds[192 * 40];    // [192 rows][40] (32 used, 80B stride)
  __shared__ u16 k_lds[192 * 40];    // chunk of 192 key rows
  __shared__ u16 vt_lds[24 * 320];   // [24 tiles (jt16 x ns)][16 d][20]
  __shared__ float mb[NN];

  const int bid = blockIdx.x;
  const int b = bid >> 1, half = bid & 1;
  const int t = threadIdx.x, w = t >> 6, l = t & 63;
  const int lr = l & 15, lg = l >> 4;

  for (int i = t; i < NN; i += 256)
    mb[i] = LOG2E * 1e9f * (mask[b * NN + i] - 1.0f) - SMAX;

  const int xrow_b = b * NN;
  const int qrow_loc = half * 192 + w * 48;  // wave's first q row within b
  const int itg0 = qrow_loc >> 4;            // global q-tile index base
  const f32x4 z4 = {0.f, 0.f, 0.f, 0.f};

  u32 gos[3][HH][2][2];  // stashed (g*o) bf16 frags, [ms][h][ns][pair]
  s16x8 bQ[3];
  float ls[3];
  f32x4 oa[3][2];
  u32 gatepk[3][2][2];

#pragma unroll
  for (int h = 0; h < HH; ++h) {
    __syncthreads();  // all prior LDS reads complete

    // ---- proj q + gate for wave's own 48 rows ----
    {
      s16x8 bx[3][4];
#pragma unroll
      for (int ms = 0; ms < 3; ++ms)
#pragma unroll
        for (int cs = 0; cs < 4; ++cs)
          bx[ms][cs] = *(const s16x8*)&xb[(size_t)(xrow_b + qrow_loc + ms * 16 +
                                                   lr) * CC + cs * 32 + lg * 8];
      f32x4 aq[2][3], ag[2][3];
#pragma unroll
      for (int ns = 0; ns < 2; ++ns)
#pragma unroll
        for (int ms = 0; ms < 3; ++ms) { aq[ns][ms] = z4; ag[ns][ms] = z4; }
#pragma unroll
      for (int cs = 0; cs < 4; ++cs) {
#pragma unroll
        for (int ns = 0; ns < 2; ++ns) {
          const s16x8 aqw = *(const s16x8*)&wqk[(h * 32 + ns * 16 + lr) * CC +
                                                cs * 32 + lg * 8];
          const s16x8 agw = *(const s16x8*)&wg[(h * 32 + ns * 16 + lr) * CC +
                                               cs * 32 + lg * 8];
#pragma unroll
          for (int ms = 0; ms < 3; ++ms) {
            aq[ns][ms] = MFMA32(aqw, bx[ms][cs], aq[ns][ms]);
            ag[ns][ms] = MFMA32(agw, bx[ms][cs], ag[ns][ms]);
          }
        }
      }
#pragma unroll
      for (int ns = 0; ns < 2; ++ns)
#pragma unroll
        for (int ms = 0; ms < 3; ++ms) {
          u32* dq = (u32*)q_lds + (w * 48 + ms * 16 + lr) * 20 + ns * 8 + lg * 2;
          dq[0] = pack2(aq[ns][ms][0], aq[ns][ms][1]);
          dq[1] = pack2(aq[ns][ms][2], aq[ns][ms][3]);
          float sg[4];
#pragma unroll
          for (int r = 0; r < 4; ++r)
            sg[r] = __builtin_amdgcn_rcpf(1.0f + __expf(-ag[ns][ms][r]));
          gatepk[ms][ns][0] = pack2(sg[0], sg[1]);
          gatepk[ms][ns][1] = pack2(sg[2], sg[3]);
        }
    }

#pragma unroll
    for (int ms = 0; ms < 3; ++ms) {
      ls[ms] = 0.f;
      oa[ms][0] = z4;
      oa[ms][1] = z4;
    }
    const u32* bbf = (const u32*)biasf + (size_t)h * 73728;

    // ---- key chunks: proj k,v into LDS, then attend ----
#pragma unroll
    for (int c = 0; c < 2; ++c) {
      if (c == 1) __syncthreads();  // chunk-0 attention reads done
      {
        s16x8 bx2[3][4];
#pragma unroll
        for (int ms = 0; ms < 3; ++ms)
#pragma unroll
          for (int cs = 0; cs < 4; ++cs)
            bx2[ms][cs] =
                *(const s16x8*)&xb[(size_t)(xrow_b + c * 192 + w * 48 +
                                            ms * 16 + lr) * CC + cs * 32 + lg * 8];
        f32x4 ak2[2][3], av2[2][3];
#pragma unroll
        for (int ns = 0; ns < 2; ++ns)
#pragma unroll
          for (int ms = 0; ms < 3; ++ms) { ak2[ns][ms] = z4; av2[ns][ms] = z4; }
#pragma unroll
        for (int cs = 0; cs < 4; ++cs) {
#pragma unroll
          for (int ns = 0; ns < 2; ++ns) {
            const s16x8 akw =
                *(const s16x8*)&wqk[(128 + h * 32 + ns * 16 + lr) * CC +
                                    cs * 32 + lg * 8];
            const s16x8 avw = *(const s16x8*)&wv[(h * 32 + ns * 16 + lr) * CC +
                                                 cs * 32 + lg * 8];
#pragma unroll
            for (int ms = 0; ms < 3; ++ms) {
              ak2[ns][ms] = MFMA32(akw, bx2[ms][cs], ak2[ns][ms]);
              av2[ns][ms] = MFMA32(avw, bx2[ms][cs], av2[ns][ms]);
            }
          }
        }
#pragma unroll
        for (int ns = 0; ns < 2; ++ns)
#pragma unroll
          for (int ms = 0; ms < 3; ++ms) {
            u32* dk = (u32*)k_lds + (w * 48 + ms * 16 + lr) * 20 + ns * 8 + lg * 2;
            dk[0] = pack2(ak2[ns][ms][0], ak2[ns][ms][1]);
            dk[1] = pack2(ak2[ns][ms][2], ak2[ns][ms][3]);
            const int tt = (w * 3 + ms) * 2 + ns;
#pragma unroll
            for (int r = 0; r < 4; ++r)
              vt_lds[tt * 320 + (lg * 4 + r) * 20 + lr] = f2b(av2[ns][ms][r]);
          }
      }
      __syncthreads();  // k/vt (and q on c==0) visible

      if (c == 0) {
#pragma unroll
        for (int ms = 0; ms < 3; ++ms)
          bQ[ms] = *(const s16x8*)&q_lds[(w * 48 + ms * 16 + lr) * 40 + lg * 8];
      }

#pragma unroll
      for (int ktl = 0; ktl < 3; ++ktl) {
        const int ktg = c * 3 + ktl;
        s16x8 aK[4];
#pragma unroll
        for (int js = 0; js < 4; ++js)
          aK[js] =
              *(const s16x8*)&k_lds[(ktl * 64 + js * 16 + lr) * 40 + lg * 8];
        u32 bw[3][4][2];
#pragma unroll
        for (int ms = 0; ms < 3; ++ms)
#pragma unroll
          for (int js = 0; js < 4; ++js) {
            const u32* p = bbf + ((ktg * 4 + js) * 24 + itg0 + ms) * 128 + l * 2;
            bw[ms][js][0] = p[0];
            bw[ms][js][1] = p[1];
          }
        s16x4 aV[4][2];
#pragma unroll
        for (int st = 0; st < 4; ++st)
#pragma unroll
          for (int ns = 0; ns < 2; ++ns)
            aV[st][ns] = *(const s16x4*)&vt_lds[((ktl * 4 + st) * 2 + ns) * 320 +
                                                lr * 20 + lg * 4];

        f32x4 sT[3][4];
#pragma unroll
        for (int ms = 0; ms < 3; ++ms)
#pragma unroll
          for (int js = 0; js < 4; ++js) sT[ms][js] = MFMA32(aK[js], bQ[ms], z4);

#pragma unroll
        for (int js = 0; js < 4; ++js) {
          const int jb = c * 192 + ktl * 64 + js * 16 + lg * 4;
          const f32x4 m4 = *(const f32x4*)&mb[jb];
#pragma unroll
          for (int ms = 0; ms < 3; ++ms) {
            const u32 b0 = bw[ms][js][0], b1 = bw[ms][js][1];
            sT[ms][js][0] += b2f_lo(b0) + m4[0];
            sT[ms][js][1] += b2f_hi(b0) + m4[1];
            sT[ms][js][2] += b2f_lo(b1) + m4[2];
            sT[ms][js][3] += b2f_hi(b1) + m4[3];
          }
        }

        u32 pk[3][4][2];
#pragma unroll
        for (int ms = 0; ms < 3; ++ms) {
          float ts = 0.f;
#pragma unroll
          for (int js = 0; js < 4; ++js)
#pragma unroll
            for (int r = 0; r < 4; ++r) {
              const float p = exp2f(sT[ms][js][r]);
              sT[ms][js][r] = p;
              ts += p;
            }
          ts += __shfl_xor(ts, 16);
          ts += __shfl_xor(ts, 32);
          ls[ms] += ts;
#pragma unroll
          for (int js = 0; js < 4; ++js) {
            pk[ms][js][0] = pack2t(sT[ms][js][0], sT[ms][js][1]);
            pk[ms][js][1] = pack2t(sT[ms][js][2], sT[ms][js][3]);
          }
        }

#pragma unroll
        for (int st = 0; st < 4; ++st)
#pragma unroll
          for (int ms = 0; ms < 3; ++ms) {
            const s16x4 pb = mk4(pk[ms][st][0], pk[ms][st][1]);
#pragma unroll
            for (int ns = 0; ns < 2; ++ns)
              oa[ms][ns] = MFMA16(aV[st][ns], pb, oa[ms][ns]);
          }
      }
    }

    // ---- head epilogue: (g*o/ls) -> bf16 stash ----
#pragma unroll
    for (int ms = 0; ms < 3; ++ms) {
      const float inv = __builtin_amdgcn_rcpf(ls[ms]);
#pragma unroll
      for (int ns = 0; ns < 2; ++ns) {
        const float g0 = b2f_lo(gatepk[ms][ns][0]);
        const float g1 = b2f_hi(gatepk[ms][ns][0]);
        const float g2 = b2f_lo(gatepk[ms][ns][1]);
        const float g3 = b2f_hi(gatepk[ms][ns][1]);
        const float v0 = oa[ms][ns][0] * inv * g0;
        const float v1 = oa[ms][ns][1] * inv * g1;
        const float v2 = oa[ms][ns][2] * inv * g2;
        const float v3 = oa[ms][ns][3] * inv * g3;
        gos[ms][h][ns][0] = pack2(v0, v1);
        gos[ms][h][ns][1] = pack2(v2, v3);
      }
    }
  }

  // ---- out-projection: out^T = wo * (g*o)^T, all from registers ----
  f32x4 acc2[8][3];
#pragma unroll
  for (int ns2 = 0; ns2 < 8; ++ns2)
#pragma unroll
    for (int ms = 0; ms < 3; ++ms) acc2[ns2][ms] = z4;
#pragma unroll
  for (int h2 = 0; h2 < HH; ++h2)
#pragma unroll
    for (int ns = 0; ns < 2; ++ns)
#pragma unroll
      for (int ns2 = 0; ns2 < 8; ++ns2) {
        const s16x4 aW = *(const s16x4*)&wo[(ns2 * 16 + lr) * CC + h2 * 32 +
                                            ns * 16 + lg * 4];
#pragma unroll
        for (int ms = 0; ms < 3; ++ms)
          acc2[ns2][ms] =
              MFMA16(aW, mk4(gos[ms][h2][ns][0], gos[ms][h2][ns][1]),
                     acc2[ns2][ms]);
      }
#pragma unroll
  for (int ms = 0; ms < 3; ++ms) {
    float* orow = io + (size_t)(xrow_b + qrow_loc + ms * 16 + lr) * CC;
#pragma unroll
    for (int ns2 = 0; ns2 < 8; ++ns2)
      *(f32x4*)&orow[ns2 * 16 + lg * 4] = acc2[ns2][ms];
  }
}

// ---------------------------------------------------------------------------
extern "C" void kernel_launch(void* const* d_in, const int* in_sizes, int n_in,
                              void* d_out, int out_size, void* d_ws,
                              size_t ws_size, hipStream_t stream) {
  const float* pair = (const float*)d_in[0];
  const float* mask = (const float*)d_in[1];
  const float* ln_w = (const float*)d_in[2];
  const float* ln_b = (const float*)d_in[3];
  const float* bias_w = (const float*)d_in[4];
  const float* q_w = (const float*)d_in[5];
  const float* k_w = (const float*)d_in[6];
  const float* v_w = (const float*)d_in[7];
  const float* g_w = (const float*)d_in[8];
  const float* o_w = (const float*)d_in[9];

  char* wsb = (char*)d_ws;
  u16* xb = (u16*)wsb;                  // 37,748,736 B
  u16* biasf = (u16*)(wsb + 37748736);  //  1,179,648 B (bf16 frag-tiled, *log2e)
  u16* wqk = (u16*)(wsb + 38928384);    //     65,536 B (q*scale*log2e | k)
  u16* wv = (u16*)(wsb + 38993920);     //     32,768 B
  u16* wg = (u16*)(wsb + 39026688);     //     32,768 B
  u16* wo = (u16*)(wsb + 39059456);     //     32,768 B
  float* io = (float*)d_out;

  hipLaunchKernelGGL(k_ln_bias, dim3(NN * NN / 4 + 1), dim3(256), 0, stream,
                     pair, ln_w, ln_b, bias_w, q_w, k_w, v_w, g_w, o_w, xb,
                     biasf, wqk, wv, wg, wo);
  hipLaunchKernelGGL(k_mega, dim3(NN * 2), dim3(256), 0, stream, xb, wqk, wv,
                     wg, wo, biasf, mask, io);
}